// Round 1
// baseline (987.250 us; speedup 1.0000x reference)
//
#include <hip/hip_runtime.h>

// Grid constants (match the JAX reference)
#define NX   480
#define NXC  960
#define NS   (480*480)     // 230400 spatial cells, pooled / direct grids
#define NSC  (960*960)     // 921600 spatial cells, 'cen' grids
#define CC   64            // channels per source
#define BB   2             // batch

// ---------------------------------------------------------------------------
// Pass 1a: direct scatter winner — last point index wins (atomicMax on p)
// ---------------------------------------------------------------------------
__global__ void scatter_winner(const int* __restrict__ coords, int P,
                               int* __restrict__ winner /* [B*NS], init -1 */) {
    int p = blockIdx.x * blockDim.x + threadIdx.x;
    if (p >= P) return;
    int b = coords[4*p + 0];
    int y = coords[4*p + 2];
    int x = coords[4*p + 3];
    atomicMax(&winner[b*NS + y*NX + x], p);
}

// ---------------------------------------------------------------------------
// Pass 1b: cen scatter winner (960x960 cell winner) + pooled-block winner.
// The max p in a 2x2 block is always the winner of its own cell, so the
// pooled winner is guaranteed to be a valid cell winner.
// ---------------------------------------------------------------------------
__global__ void scatter_winner_cen(const int* __restrict__ coords, int P,
                                   int* __restrict__ winner        /* [B*NSC] */,
                                   int* __restrict__ pooled_winner /* [B*NS]  */) {
    int p = blockIdx.x * blockDim.x + threadIdx.x;
    if (p >= P) return;
    int b = coords[4*p + 0];
    int y = coords[4*p + 2];
    int x = coords[4*p + 3];
    atomicMax(&winner[b*NSC + y*NXC + x], p);
    atomicMax(&pooled_winner[b*NS + (y >> 1)*NX + (x >> 1)], p);
}

// ---------------------------------------------------------------------------
// Pass 2a: direct sources (lidar, radar) — winning point writes its 64
// channels to both the standalone output and its cat section.
// blockDim = (64 channels, 4 points)
// ---------------------------------------------------------------------------
__global__ void write_direct(const float* __restrict__ feat,
                             const int* __restrict__ coords, int P,
                             const int* __restrict__ winner,
                             float* __restrict__ direct,  // [B,64,NS]
                             float* __restrict__ cat,     // [B,256,NS]
                             int choff) {
    int p = blockIdx.x * blockDim.y + threadIdx.y;
    if (p >= P) return;
    int c = threadIdx.x;
    int b = coords[4*p + 0];
    int y = coords[4*p + 2];
    int x = coords[4*p + 3];
    int s = y*NX + x;
    if (winner[b*NS + s] != p) return;   // not the last writer of this cell
    float v = feat[p*CC + c];
    direct[((size_t)b*CC + c)*NS + s] = v;
    cat[((size_t)b*256 + choff + c)*NS + s] = v;
}

// ---------------------------------------------------------------------------
// Pass 2b: cen sources — one pooled-block winner per 2x2 block gathers the
// 4 sub-cell winners and computes the exact maxpool (empty cell -> 0.0,
// all-4-occupied keeps true negative max). Writes only to cat.
// blockDim = (64 channels, 4 points)
// ---------------------------------------------------------------------------
__global__ void write_cen(const float* __restrict__ feat,
                          const int* __restrict__ coords, int P,
                          const int* __restrict__ winner,        // [B*NSC]
                          const int* __restrict__ pooled_winner, // [B*NS]
                          float* __restrict__ cat,               // [B,256,NS]
                          int choff) {
    int p = blockIdx.x * blockDim.y + threadIdx.y;
    if (p >= P) return;
    int c = threadIdx.x;
    int b = coords[4*p + 0];
    int y = coords[4*p + 2];
    int x = coords[4*p + 3];
    int ps = (y >> 1)*NX + (x >> 1);
    if (pooled_winner[b*NS + ps] != p) return;  // one representative per block
    int y0 = y & ~1, x0 = x & ~1;
    const int* wb = &winner[(size_t)b*NSC];
    int w0 = wb[ y0   *NXC + x0    ];
    int w1 = wb[ y0   *NXC + x0 + 1];
    int w2 = wb[(y0+1)*NXC + x0    ];
    int w3 = wb[(y0+1)*NXC + x0 + 1];
    float v =        (w0 < 0) ? 0.0f : feat[(size_t)w0*CC + c];
    v = fmaxf(v,     (w1 < 0) ? 0.0f : feat[(size_t)w1*CC + c]);
    v = fmaxf(v,     (w2 < 0) ? 0.0f : feat[(size_t)w2*CC + c]);
    v = fmaxf(v,     (w3 < 0) ? 0.0f : feat[(size_t)w3*CC + c]);
    cat[((size_t)b*256 + choff + c)*NS + ps] = v;
}

extern "C" void kernel_launch(void* const* d_in, const int* in_sizes, int n_in,
                              void* d_out, int out_size, void* d_ws, size_t ws_size,
                              hipStream_t stream) {
    // Inputs per setup_inputs() order
    const float* rc_feat   = (const float*)d_in[0];  // radar_cen
    const int*   rc_coords = (const int*)  d_in[1];
    const float* lc_feat   = (const float*)d_in[2];  // lidar_cen
    const int*   lc_coords = (const int*)  d_in[3];
    const float* l_feat    = (const float*)d_in[4];  // lidar
    const int*   l_coords  = (const int*)  d_in[5];
    const float* r_feat    = (const float*)d_in[6];  // radar
    const int*   r_coords  = (const int*)  d_in[7];

    int P_rc = in_sizes[0] / CC;
    int P_lc = in_sizes[2] / CC;
    int P_l  = in_sizes[4] / CC;
    int P_r  = in_sizes[6] / CC;

    // Output layout (flat, in return order): lidar, radar, cat
    float* out_lidar = (float*)d_out;                 // [2,64,480,480]
    float* out_radar = out_lidar + (size_t)BB*CC*NS;  // [2,64,480,480]
    float* out_cat   = out_radar + (size_t)BB*CC*NS;  // [2,256,480,480]

    // Workspace layout (ints): winner grids, init to -1 (memset 0xFF)
    int* w_l   = (int*)d_ws;           // [B*NS]
    int* w_r   = w_l   + BB*NS;        // [B*NS]
    int* w_lc  = w_r   + BB*NS;        // [B*NSC]
    int* w_rc  = w_lc  + BB*NSC;       // [B*NSC]
    int* pw_lc = w_rc  + BB*NSC;       // [B*NS]
    int* pw_rc = pw_lc + BB*NS;        // [B*NS]
    size_t ws_bytes = (size_t)(4*BB*NS + 2*BB*NSC) * sizeof(int);  // ~22.1 MB

    // Zero the full output (background of every scatter) and -1 the winners.
    size_t out_bytes = (size_t)(2*BB*CC*NS + BB*4*CC*NS) * sizeof(float);
    hipMemsetAsync(d_out, 0,   out_bytes, stream);
    hipMemsetAsync(d_ws, 0xFF, ws_bytes,  stream);

    // Pass 1: winner resolution
    scatter_winner<<<(P_l  + 255)/256, 256, 0, stream>>>(l_coords, P_l, w_l);
    scatter_winner<<<(P_r  + 255)/256, 256, 0, stream>>>(r_coords, P_r, w_r);
    scatter_winner_cen<<<(P_lc + 255)/256, 256, 0, stream>>>(lc_coords, P_lc, w_lc, pw_lc);
    scatter_winner_cen<<<(P_rc + 255)/256, 256, 0, stream>>>(rc_coords, P_rc, w_rc, pw_rc);

    // Pass 2: feature writes
    dim3 blk(64, 4);
    write_direct<<<(P_l  + 3)/4, blk, 0, stream>>>(l_feat,  l_coords,  P_l,  w_l,  out_lidar, out_cat, 0);
    write_direct<<<(P_r  + 3)/4, blk, 0, stream>>>(r_feat,  r_coords,  P_r,  w_r,  out_radar, out_cat, 128);
    write_cen   <<<(P_lc + 3)/4, blk, 0, stream>>>(lc_feat, lc_coords, P_lc, w_lc, pw_lc, out_cat, 64);
    write_cen   <<<(P_rc + 3)/4, blk, 0, stream>>>(rc_feat, rc_coords, P_rc, w_rc, pw_rc, out_cat, 192);
}

// Round 2
// 751.933 us; speedup vs baseline: 1.3129x; 1.3129x over previous
//
#include <hip/hip_runtime.h>

// Grid constants (match the JAX reference)
#define NX   480
#define NXC  960
#define NS   (480*480)     // 230400 spatial cells (direct / pooled grids)
#define NSC  (960*960)     // 921600 spatial cells ('cen' grids)
#define CC   64            // channels per source
#define BB   2             // batch

// ---------------------------------------------------------------------------
// Pass 1: winner resolution — last point index wins (atomicMax on p).
// ---------------------------------------------------------------------------
__global__ void scatter_winner(const int* __restrict__ coords, int P, int nx, int ns,
                               int* __restrict__ winner /* [B*ns], init -1 */) {
    int p = blockIdx.x * blockDim.x + threadIdx.x;
    if (p >= P) return;
    int b = coords[4*p + 0];
    int y = coords[4*p + 2];
    int x = coords[4*p + 3];
    atomicMax(&winner[b*ns + y*nx + x], p);
}

__device__ __forceinline__ float term(int w, const float* __restrict__ f, int c) {
    // empty cell contributes 0 (the scatter background), occupied contributes feat
    return (w < 0) ? 0.0f : f[(size_t)w * CC + c];
}

// ---------------------------------------------------------------------------
// Pass 2: dense gather-write. Every output element written exactly once,
// coalesced float4 stores. Each thread owns 4 consecutive spatial cells
// (480 % 4 == 0, so the quad never crosses a row). grid = (NS/1024, B, 4),
// blockDim = 256; grid.z splits the 64 channels into 4 chunks of 16 for
// more resident waves (winner loads re-hit L2).
// ---------------------------------------------------------------------------
__global__ void __launch_bounds__(256)
dense_write(const float* __restrict__ lf,  const float* __restrict__ rf,
            const float* __restrict__ lcf, const float* __restrict__ rcf,
            const int* __restrict__ wl,  const int* __restrict__ wr,
            const int* __restrict__ wlc, const int* __restrict__ wrc,
            float* __restrict__ out_l, float* __restrict__ out_r,
            float* __restrict__ out_cat) {
    int s = (blockIdx.x * 256 + threadIdx.x) * 4;   // first of 4 cells
    int b = blockIdx.y;
    int c0 = blockIdx.z * 16;                        // channel chunk

    // direct winners (4 cells)
    int4 v_l = *(const int4*)(wl + (size_t)b*NS + s);
    int4 v_r = *(const int4*)(wr + (size_t)b*NS + s);
    int wla[4] = {v_l.x, v_l.y, v_l.z, v_l.w};
    int wra[4] = {v_r.x, v_r.y, v_r.z, v_r.w};

    // cen sub-cell winners: rows 2*py, 2*py+1, cols 2*px .. 2*px+7
    int py = s / NX, px = s - py * NX;
    int y0 = py * 2, x0 = px * 2;                    // x0 is 8-aligned
    const int* blc = wlc + (size_t)b * NSC;
    const int* brc = wrc + (size_t)b * NSC;
    int4 lt0 = *(const int4*)(blc + (size_t)y0*NXC + x0);
    int4 lt1 = *(const int4*)(blc + (size_t)y0*NXC + x0 + 4);
    int4 lb0 = *(const int4*)(blc + (size_t)(y0+1)*NXC + x0);
    int4 lb1 = *(const int4*)(blc + (size_t)(y0+1)*NXC + x0 + 4);
    int4 rt0 = *(const int4*)(brc + (size_t)y0*NXC + x0);
    int4 rt1 = *(const int4*)(brc + (size_t)y0*NXC + x0 + 4);
    int4 rb0 = *(const int4*)(brc + (size_t)(y0+1)*NXC + x0);
    int4 rb1 = *(const int4*)(brc + (size_t)(y0+1)*NXC + x0 + 4);
    int lct[8] = {lt0.x, lt0.y, lt0.z, lt0.w, lt1.x, lt1.y, lt1.z, lt1.w};
    int lcb[8] = {lb0.x, lb0.y, lb0.z, lb0.w, lb1.x, lb1.y, lb1.z, lb1.w};
    int rct[8] = {rt0.x, rt0.y, rt0.z, rt0.w, rt1.x, rt1.y, rt1.z, rt1.w};
    int rcb[8] = {rb0.x, rb0.y, rb0.z, rb0.w, rb1.x, rb1.y, rb1.z, rb1.w};

    size_t so  = (size_t)b * CC  * NS + s;   // direct-output base
    size_t co  = (size_t)b * 256 * NS + s;   // cat base

    for (int cc = 0; cc < 16; ++cc) {
        int c = c0 + cc;
        float vl[4], vr[4], vlc[4], vrc[4];
        #pragma unroll
        for (int j = 0; j < 4; ++j) {
            vl[j] = term(wla[j], lf, c);
            vr[j] = term(wra[j], rf, c);
            float a = term(lct[2*j], lcf, c);
            a = fmaxf(a, term(lct[2*j+1], lcf, c));
            a = fmaxf(a, term(lcb[2*j],   lcf, c));
            a = fmaxf(a, term(lcb[2*j+1], lcf, c));
            vlc[j] = a;
            float m = term(rct[2*j], rcf, c);
            m = fmaxf(m, term(rct[2*j+1], rcf, c));
            m = fmaxf(m, term(rcb[2*j],   rcf, c));
            m = fmaxf(m, term(rcb[2*j+1], rcf, c));
            vrc[j] = m;
        }
        float4 fvl = make_float4(vl[0], vl[1], vl[2], vl[3]);
        float4 fvr = make_float4(vr[0], vr[1], vr[2], vr[3]);
        float4 fvlc = make_float4(vlc[0], vlc[1], vlc[2], vlc[3]);
        float4 fvrc = make_float4(vrc[0], vrc[1], vrc[2], vrc[3]);
        *(float4*)(out_l   + so + (size_t)c * NS)        = fvl;
        *(float4*)(out_r   + so + (size_t)c * NS)        = fvr;
        *(float4*)(out_cat + co + (size_t)c * NS)        = fvl;   // lidar     -> ch   0..63
        *(float4*)(out_cat + co + (size_t)(64  + c)*NS)  = fvlc;  // lidar_cen -> ch  64..127
        *(float4*)(out_cat + co + (size_t)(128 + c)*NS)  = fvr;   // radar     -> ch 128..191
        *(float4*)(out_cat + co + (size_t)(192 + c)*NS)  = fvrc;  // radar_cen -> ch 192..255
    }
}

extern "C" void kernel_launch(void* const* d_in, const int* in_sizes, int n_in,
                              void* d_out, int out_size, void* d_ws, size_t ws_size,
                              hipStream_t stream) {
    // Inputs per setup_inputs() order
    const float* rc_feat   = (const float*)d_in[0];  // radar_cen
    const int*   rc_coords = (const int*)  d_in[1];
    const float* lc_feat   = (const float*)d_in[2];  // lidar_cen
    const int*   lc_coords = (const int*)  d_in[3];
    const float* l_feat    = (const float*)d_in[4];  // lidar
    const int*   l_coords  = (const int*)  d_in[5];
    const float* r_feat    = (const float*)d_in[6];  // radar
    const int*   r_coords  = (const int*)  d_in[7];

    int P_rc = in_sizes[0] / CC;
    int P_lc = in_sizes[2] / CC;
    int P_l  = in_sizes[4] / CC;
    int P_r  = in_sizes[6] / CC;

    // Output layout (flat, in return order): lidar, radar, cat
    float* out_lidar = (float*)d_out;                 // [2,64,480,480]
    float* out_radar = out_lidar + (size_t)BB*CC*NS;  // [2,64,480,480]
    float* out_cat   = out_radar + (size_t)BB*CC*NS;  // [2,256,480,480]

    // Workspace: winner grids only, init -1 (memset 0xFF)
    int* w_l  = (int*)d_ws;          // [B*NS]
    int* w_r  = w_l  + BB*NS;        // [B*NS]
    int* w_lc = w_r  + BB*NS;        // [B*NSC]
    int* w_rc = w_lc + BB*NSC;       // [B*NSC]
    size_t ws_bytes = (size_t)(2*BB*NS + 2*BB*NSC) * sizeof(int);  // ~18.4 MB

    hipMemsetAsync(d_ws, 0xFF, ws_bytes, stream);

    // Pass 1: winner resolution (tiny)
    scatter_winner<<<(P_l  + 255)/256, 256, 0, stream>>>(l_coords,  P_l,  NX,  NS,  w_l);
    scatter_winner<<<(P_r  + 255)/256, 256, 0, stream>>>(r_coords,  P_r,  NX,  NS,  w_r);
    scatter_winner<<<(P_lc + 255)/256, 256, 0, stream>>>(lc_coords, P_lc, NXC, NSC, w_lc);
    scatter_winner<<<(P_rc + 255)/256, 256, 0, stream>>>(rc_coords, P_rc, NXC, NSC, w_rc);

    // Pass 2: dense gather-write of all 708 MB, fully coalesced
    dim3 grid(NS / (256 * 4), BB, 4);
    dense_write<<<grid, 256, 0, stream>>>(l_feat, r_feat, lc_feat, rc_feat,
                                          w_l, w_r, w_lc, w_rc,
                                          out_lidar, out_radar, out_cat);
}

// Round 3
// 739.553 us; speedup vs baseline: 1.3349x; 1.0167x over previous
//
#include <hip/hip_runtime.h>

// Grid constants (match the JAX reference)
#define NX   480
#define NXC  960
#define NS   (480*480)     // 230400 spatial cells (direct / pooled grids)
#define NSC  (960*960)     // 921600 spatial cells ('cen' grids)
#define CC   64            // channels per source
#define BB   2             // batch

typedef float f4v __attribute__((ext_vector_type(4)));

__device__ __forceinline__ void nt_store4(float* p, float a, float b, float c, float d) {
    f4v v = {a, b, c, d};
    __builtin_nontemporal_store(v, (f4v*)p);
}

// ---------------------------------------------------------------------------
// Pass 1: winner resolution — last point index wins (atomicMax on p).
// All four sources in one dispatch (blockIdx.y selects the source).
// ---------------------------------------------------------------------------
struct SrcDesc { const int* coords; int* winner; int P; int nx; int ns; };

__global__ void __launch_bounds__(256)
scatter_winner4(SrcDesc s0, SrcDesc s1, SrcDesc s2, SrcDesc s3) {
    SrcDesc d = (blockIdx.y == 0) ? s0 : (blockIdx.y == 1) ? s1
              : (blockIdx.y == 2) ? s2 : s3;
    int p = blockIdx.x * 256 + threadIdx.x;
    if (p >= d.P) return;
    int b = d.coords[4*p + 0];
    int y = d.coords[4*p + 2];
    int x = d.coords[4*p + 3];
    atomicMax(&d.winner[b*d.ns + y*d.nx + x], p);
}

__device__ __forceinline__ float term(int w, const float* __restrict__ f, int c) {
    // empty cell contributes 0 (the scatter background), occupied contributes feat
    return (w < 0) ? 0.0f : f[(size_t)w * CC + c];
}

// ---------------------------------------------------------------------------
// Pass 2: dense gather-write. Every output element written exactly once with
// coalesced non-temporal float4 stores (output is write-once, no-reuse — keep
// it out of L2 so the feature tables / winner grids stay resident).
// Each thread owns 4 consecutive spatial cells (480 % 4 == 0, quad never
// crosses a row). grid = (NS/1024, B, 2); blockDim = 256; grid.z splits the
// 64 channels into 2 chunks of 32 (winner regs reused across the c-loop).
// ---------------------------------------------------------------------------
__global__ void __launch_bounds__(256)
dense_write(const float* __restrict__ lf,  const float* __restrict__ rf,
            const float* __restrict__ lcf, const float* __restrict__ rcf,
            const int* __restrict__ wl,  const int* __restrict__ wr,
            const int* __restrict__ wlc, const int* __restrict__ wrc,
            float* __restrict__ out_l, float* __restrict__ out_r,
            float* __restrict__ out_cat) {
    int s = (blockIdx.x * 256 + threadIdx.x) * 4;   // first of 4 cells
    int b = blockIdx.y;
    int c0 = blockIdx.z * 32;                        // channel chunk

    // direct winners (4 cells)
    int4 v_l = *(const int4*)(wl + (size_t)b*NS + s);
    int4 v_r = *(const int4*)(wr + (size_t)b*NS + s);
    int wla[4] = {v_l.x, v_l.y, v_l.z, v_l.w};
    int wra[4] = {v_r.x, v_r.y, v_r.z, v_r.w};

    // cen sub-cell winners: rows 2*py, 2*py+1, cols 2*px .. 2*px+7
    int py = s / NX, px = s - py * NX;
    int y0 = py * 2, x0 = px * 2;                    // x0 is 8-aligned
    const int* blc = wlc + (size_t)b * NSC;
    const int* brc = wrc + (size_t)b * NSC;
    int4 lt0 = *(const int4*)(blc + (size_t)y0*NXC + x0);
    int4 lt1 = *(const int4*)(blc + (size_t)y0*NXC + x0 + 4);
    int4 lb0 = *(const int4*)(blc + (size_t)(y0+1)*NXC + x0);
    int4 lb1 = *(const int4*)(blc + (size_t)(y0+1)*NXC + x0 + 4);
    int4 rt0 = *(const int4*)(brc + (size_t)y0*NXC + x0);
    int4 rt1 = *(const int4*)(brc + (size_t)y0*NXC + x0 + 4);
    int4 rb0 = *(const int4*)(brc + (size_t)(y0+1)*NXC + x0);
    int4 rb1 = *(const int4*)(brc + (size_t)(y0+1)*NXC + x0 + 4);
    int lct[8] = {lt0.x, lt0.y, lt0.z, lt0.w, lt1.x, lt1.y, lt1.z, lt1.w};
    int lcb[8] = {lb0.x, lb0.y, lb0.z, lb0.w, lb1.x, lb1.y, lb1.z, lb1.w};
    int rct[8] = {rt0.x, rt0.y, rt0.z, rt0.w, rt1.x, rt1.y, rt1.z, rt1.w};
    int rcb[8] = {rb0.x, rb0.y, rb0.z, rb0.w, rb1.x, rb1.y, rb1.z, rb1.w};

    size_t so  = (size_t)b * CC  * NS + s;   // direct-output base
    size_t co  = (size_t)b * 256 * NS + s;   // cat base

    for (int cc = 0; cc < 32; ++cc) {
        int c = c0 + cc;
        float vl[4], vr[4], vlc[4], vrc[4];
        #pragma unroll
        for (int j = 0; j < 4; ++j) {
            vl[j] = term(wla[j], lf, c);
            vr[j] = term(wra[j], rf, c);
            float a = term(lct[2*j], lcf, c);
            a = fmaxf(a, term(lct[2*j+1], lcf, c));
            a = fmaxf(a, term(lcb[2*j],   lcf, c));
            a = fmaxf(a, term(lcb[2*j+1], lcf, c));
            vlc[j] = a;
            float m = term(rct[2*j], rcf, c);
            m = fmaxf(m, term(rct[2*j+1], rcf, c));
            m = fmaxf(m, term(rcb[2*j],   rcf, c));
            m = fmaxf(m, term(rcb[2*j+1], rcf, c));
            vrc[j] = m;
        }
        nt_store4(out_l   + so + (size_t)c * NS,       vl[0],  vl[1],  vl[2],  vl[3]);
        nt_store4(out_r   + so + (size_t)c * NS,       vr[0],  vr[1],  vr[2],  vr[3]);
        nt_store4(out_cat + co + (size_t)c * NS,       vl[0],  vl[1],  vl[2],  vl[3]);   // lidar     ch   0..63
        nt_store4(out_cat + co + (size_t)(64 +c)*NS,   vlc[0], vlc[1], vlc[2], vlc[3]);  // lidar_cen ch  64..127
        nt_store4(out_cat + co + (size_t)(128+c)*NS,   vr[0],  vr[1],  vr[2],  vr[3]);   // radar     ch 128..191
        nt_store4(out_cat + co + (size_t)(192+c)*NS,   vrc[0], vrc[1], vrc[2], vrc[3]);  // radar_cen ch 192..255
    }
}

extern "C" void kernel_launch(void* const* d_in, const int* in_sizes, int n_in,
                              void* d_out, int out_size, void* d_ws, size_t ws_size,
                              hipStream_t stream) {
    // Inputs per setup_inputs() order
    const float* rc_feat   = (const float*)d_in[0];  // radar_cen
    const int*   rc_coords = (const int*)  d_in[1];
    const float* lc_feat   = (const float*)d_in[2];  // lidar_cen
    const int*   lc_coords = (const int*)  d_in[3];
    const float* l_feat    = (const float*)d_in[4];  // lidar
    const int*   l_coords  = (const int*)  d_in[5];
    const float* r_feat    = (const float*)d_in[6];  // radar
    const int*   r_coords  = (const int*)  d_in[7];

    int P_rc = in_sizes[0] / CC;
    int P_lc = in_sizes[2] / CC;
    int P_l  = in_sizes[4] / CC;
    int P_r  = in_sizes[6] / CC;

    // Output layout (flat, in return order): lidar, radar, cat
    float* out_lidar = (float*)d_out;                 // [2,64,480,480]
    float* out_radar = out_lidar + (size_t)BB*CC*NS;  // [2,64,480,480]
    float* out_cat   = out_radar + (size_t)BB*CC*NS;  // [2,256,480,480]

    // Workspace: winner grids only, init -1 (memset 0xFF)
    int* w_l  = (int*)d_ws;          // [B*NS]
    int* w_r  = w_l  + BB*NS;        // [B*NS]
    int* w_lc = w_r  + BB*NS;        // [B*NSC]
    int* w_rc = w_lc + BB*NSC;       // [B*NSC]
    size_t ws_bytes = (size_t)(2*BB*NS + 2*BB*NSC) * sizeof(int);  // ~18.4 MB

    hipMemsetAsync(d_ws, 0xFF, ws_bytes, stream);

    // Pass 1: winner resolution, one dispatch for all four sources
    SrcDesc s_l  = { l_coords,  w_l,  P_l,  NX,  NS  };
    SrcDesc s_r  = { r_coords,  w_r,  P_r,  NX,  NS  };
    SrcDesc s_lc = { lc_coords, w_lc, P_lc, NXC, NSC };
    SrcDesc s_rc = { rc_coords, w_rc, P_rc, NXC, NSC };
    int maxP = max(max(P_l, P_r), max(P_lc, P_rc));
    dim3 wgrid((maxP + 255) / 256, 4);
    scatter_winner4<<<wgrid, 256, 0, stream>>>(s_l, s_r, s_lc, s_rc);

    // Pass 2: dense gather-write of all 708 MB, fully coalesced nt-stores
    dim3 grid(NS / (256 * 4), BB, 2);
    dense_write<<<grid, 256, 0, stream>>>(l_feat, r_feat, lc_feat, rc_feat,
                                          w_l, w_r, w_lc, w_rc,
                                          out_lidar, out_radar, out_cat);
}